// Round 2
// baseline (690.169 us; speedup 1.0000x reference)
//
#include <hip/hip_runtime.h>
#include <math.h>

// ---------------------------------------------------------------------------
// Single fused kernel: int4 weight quant (per-block, into LDS) +
// maxpool(2^3) + linear(2048->4) + bias + softmax.
//
// Grid 1024 x 512 threads. Each block:
//   Phase 1: block-wide max|W| (W = 32 KB, L2/L3-broadcast across blocks).
//   Phase 2: dequantize W into a 32 KB LDS table wlds[f][o] (transposed so
//            one float4 read yields all 4 output channels of feature f).
//   Phase 3: 8 waves x 8 batch items; each wave streams its 64 KB x-slice
//            fully contiguously (16 B/lane dense), pools in-register +
//            one __shfl_xor(4) for h-pairs, FMAs against LDS weights,
//            in-wave butterfly reduce, softmax, write float4.
//
// No workspace, no second dispatch, no cross-wave sync after phase 2.
// Occupancy: 32.8 KB LDS -> 4 blocks/CU = 32 waves/CU (max).
// ---------------------------------------------------------------------------
__global__ __launch_bounds__(512) void fused_all(
        const float* __restrict__ x,     // [8192][4][16][16][16]
        const float* __restrict__ W,     // [4][2048]
        const float* __restrict__ bias,  // [4]
        float* __restrict__ out) {       // [8192][4]
    __shared__ float wlds[2048 * 4];     // [feature][channel]
    __shared__ float smax[8];

    const int t = threadIdx.x;           // 0..511
    const int l = t & 63;                // lane

    // ---- Phase 1: max|W| ---------------------------------------------------
    float4 wv[4];
    float m = 0.0f;
    #pragma unroll
    for (int i = 0; i < 4; ++i) {
        wv[i] = ((const float4*)W)[t + 512 * i];     // 2048 float4 total
        m = fmaxf(m, fmaxf(fmaxf(fabsf(wv[i].x), fabsf(wv[i].y)),
                           fmaxf(fabsf(wv[i].z), fabsf(wv[i].w))));
    }
    #pragma unroll
    for (int off = 32; off; off >>= 1) m = fmaxf(m, __shfl_xor(m, off));
    if (l == 0) smax[t >> 6] = m;
    __syncthreads();
    float M = smax[0];
    #pragma unroll
    for (int i = 1; i < 8; ++i) M = fmaxf(M, smax[i]);
    const float scale = M / 7.0f;

    // ---- Phase 2: dequant -> LDS (transposed) ------------------------------
#define QSTORE(val, gidx)                                             \
    {                                                                 \
        const int g_ = (gidx);                                        \
        float q_ = rintf((val) / scale);   /* half-to-even like np */ \
        q_ = fminf(fmaxf(q_, -8.0f), 7.0f);                           \
        wlds[(g_ & 2047) * 4 + (g_ >> 11)] = q_ * scale;              \
    }
    #pragma unroll
    for (int i = 0; i < 4; ++i) {
        const int g0 = (t + 512 * i) << 2;
        QSTORE(wv[i].x, g0 + 0); QSTORE(wv[i].y, g0 + 1);
        QSTORE(wv[i].z, g0 + 2); QSTORE(wv[i].w, g0 + 3);
    }
#undef QSTORE
    __syncthreads();

    // ---- Phase 3: stream x, pool, FMA --------------------------------------
    const int wv_id = t >> 6;                      // wave 0..7
    const int b     = (blockIdx.x << 3) + wv_id;   // batch item

    const float* __restrict__ p = x + (size_t)b * 16384 + (l << 2);
    const int hodd = (l >> 2) & 1;                 // h parity
    const int f0   = hodd * 64 + (l >> 3) * 8 + ((l & 3) << 1);
    const float* wl = wlds + f0 * 4;

    float4 acc = make_float4(0.f, 0.f, 0.f, 0.f);

    #pragma unroll 4
    for (int it = 0; it < 16; ++it) {
        // 4 consecutive d-planes, 1 KB each, wave-dense contiguous
        const float4 v0 = *(const float4*)(p);
        const float4 v1 = *(const float4*)(p + 256);
        const float4 v2 = *(const float4*)(p + 512);
        const float4 v3 = *(const float4*)(p + 768);
        p += 1024;

        // w-pair + d-pair pooling in-register
        const float aA = fmaxf(fmaxf(v0.x, v0.y), fmaxf(v1.x, v1.y));
        const float bA = fmaxf(fmaxf(v0.z, v0.w), fmaxf(v1.z, v1.w));
        const float aB = fmaxf(fmaxf(v2.x, v2.y), fmaxf(v3.x, v3.y));
        const float bB = fmaxf(fmaxf(v2.z, v2.w), fmaxf(v3.z, v3.w));

        // h-pair pooling with lane^4 partner
        const float saA = __shfl_xor(aA, 4);
        const float sbA = __shfl_xor(bA, 4);
        const float saB = __shfl_xor(aB, 4);
        const float sbB = __shfl_xor(bB, 4);

        const float p0 = hodd ? fmaxf(aB, saB) : fmaxf(aA, saA);
        const float p1 = hodd ? fmaxf(bB, sbB) : fmaxf(bA, sbA);

        const float4 w0 = *(const float4*)(wl);
        const float4 w1 = *(const float4*)(wl + 4);
        wl += 512;                                  // +128 features / iter

        acc.x = fmaf(p0, w0.x, fmaf(p1, w1.x, acc.x));
        acc.y = fmaf(p0, w0.y, fmaf(p1, w1.y, acc.y));
        acc.z = fmaf(p0, w0.z, fmaf(p1, w1.z, acc.z));
        acc.w = fmaf(p0, w0.w, fmaf(p1, w1.w, acc.w));
    }

    // in-wave butterfly: all 64 lanes hold disjoint feature partial sums
    #pragma unroll
    for (int off = 32; off; off >>= 1) {
        acc.x += __shfl_xor(acc.x, off);
        acc.y += __shfl_xor(acc.y, off);
        acc.z += __shfl_xor(acc.z, off);
        acc.w += __shfl_xor(acc.w, off);
    }

    if (l == 0) {
        const float4 bi = *(const float4*)bias;
        const float l0 = acc.x + bi.x, l1 = acc.y + bi.y,
                    l2 = acc.z + bi.z, l3 = acc.w + bi.w;
        const float mm = fmaxf(fmaxf(l0, l1), fmaxf(l2, l3));
        const float e0 = expf(l0 - mm), e1 = expf(l1 - mm),
                    e2 = expf(l2 - mm), e3 = expf(l3 - mm);
        const float inv = 1.0f / (e0 + e1 + e2 + e3);
        *(float4*)(out + (size_t)b * 4) =
            make_float4(e0 * inv, e1 * inv, e2 * inv, e3 * inv);
    }
}

extern "C" void kernel_launch(void* const* d_in, const int* in_sizes, int n_in,
                              void* d_out, int out_size, void* d_ws, size_t ws_size,
                              hipStream_t stream) {
    const float* x    = (const float*)d_in[0];   // [8192,4,16,16,16]
    const float* W    = (const float*)d_in[1];   // [4,2048]
    const float* bias = (const float*)d_in[2];   // [4]
    float* out = (float*)d_out;                  // [8192,4]
    (void)d_ws; (void)ws_size;

    fused_all<<<1024, 512, 0, stream>>>(x, W, bias, out);
}

// Round 3
// 681.015 us; speedup vs baseline: 1.0134x; 1.0134x over previous
//
#include <hip/hip_runtime.h>
#include <math.h>

// ---------------------------------------------------------------------------
// Kernel 1: int4 symmetric per-tensor weight quantization (Brevitas-style).
//   scale = max|W| / 7 ;  Wq = clip(rint(W/scale), -8, 7) * scale
// Writes Wq TRANSPOSED into wqt as [2048][4] so the main kernel fetches all
// 4 output channels of a feature with one float4 load.
// 8 blocks x 256 threads: every block max-reduces the full 32 KB W (L2
// broadcast), then block bk quantize-scatters only its own 1/8 slice
// (the j==bk register chunk) -> no serial single-block write tail.
// Must run every launch: d_ws is re-poisoned before each timed call.
// ---------------------------------------------------------------------------
__global__ __launch_bounds__(256) void quant_w_kernel(
        const float* __restrict__ W, float* __restrict__ wqt /* [2048][4] */) {
    __shared__ float smax[4];
    const int t  = threadIdx.x;          // 0..255
    const int bk = blockIdx.x;           // 0..7

    float4 wv[8];
    float m = 0.0f;
    #pragma unroll
    for (int j = 0; j < 8; ++j) {
        wv[j] = ((const float4*)W)[t + 256 * j];   // whole W per block
        m = fmaxf(m, fmaxf(fmaxf(fabsf(wv[j].x), fabsf(wv[j].y)),
                           fmaxf(fabsf(wv[j].z), fabsf(wv[j].w))));
    }
    #pragma unroll
    for (int off = 32; off; off >>= 1) m = fmaxf(m, __shfl_xor(m, off));
    if ((t & 63) == 0) smax[t >> 6] = m;
    __syncthreads();
    const float M = fmaxf(fmaxf(smax[0], smax[1]), fmaxf(smax[2], smax[3]));
    const float scale = M / 7.0f;

    // quantize + transposed scatter-store this block's chunk (j == bk)
    const float4 v = wv[bk];
#define QSTORE(val, idx)                                              \
    {                                                                 \
        const int i_ = (idx);                                         \
        float q_ = rintf((val) / scale);  /* half-to-even like np */  \
        q_ = fminf(fmaxf(q_, -8.0f), 7.0f);                           \
        wqt[(i_ & 2047) * 4 + (i_ >> 11)] = q_ * scale;               \
    }
    const int i0 = (t + 256 * bk) << 2;
    QSTORE(v.x, i0 + 0); QSTORE(v.y, i0 + 1);
    QSTORE(v.z, i0 + 2); QSTORE(v.w, i0 + 3);
#undef QSTORE
}

// ---------------------------------------------------------------------------
// Kernel 2: fused maxpool(2^3) + linear(2048->4) + bias + softmax.
// ONE WAVE per batch item (4 waves / 256-thread block, grid = 2048 blocks).
// No LDS, no __syncthreads. Per iteration the wave reads 4 KB fully
// contiguous = 4 complete d-planes (16 B per lane, dense):
//   lane l -> 16B quarter-row: h = l>>2, w-quarter q = l&3, of each plane.
// Pooling: w-pairs inside the float4 (x,y | z,w), d-pairs across the two
// plane registers, h-pairs via __shfl_xor(lane^4). The two d-pairs of the
// 4-plane group are split across even-h / odd-h lanes so every lane owns
// 2 unique pooled features -> 2 float4 weight FMAs. Zero redundancy.
// Feature id: f = c*512 + dp*64 + hp*8 + wp  ==  it*128 + hodd*64 + hp*8 + 2q.
// ---------------------------------------------------------------------------
__global__ __launch_bounds__(256) void fused_pool_linear_softmax(
        const float* __restrict__ x,     // [8192][4][16][16][16]
        const float* __restrict__ wqt,   // [2048][4]
        const float* __restrict__ bias,  // [4]
        float* __restrict__ out) {       // [8192][4]
    const int t  = threadIdx.x;
    const int wv = t >> 6;                       // wave in block: 0..3
    const int l  = t & 63;                       // lane
    const int b  = (blockIdx.x << 2) + wv;       // batch item

    const float* __restrict__ p = x + (size_t)b * 16384 + (l << 2);
    const int hodd = (l >> 2) & 1;               // h parity
    const int f0   = hodd * 64 + (l >> 3) * 8 + ((l & 3) << 1);
    const float* __restrict__ wp = wqt + f0 * 4;

    float4 acc = make_float4(0.f, 0.f, 0.f, 0.f);

    #pragma unroll 4
    for (int it = 0; it < 16; ++it) {
        // 4 consecutive d-planes, 1 KB each, wave-dense contiguous
        const float4 v0 = *(const float4*)(p);        // plane d+0 (chunk A)
        const float4 v1 = *(const float4*)(p + 256);  // plane d+1 (chunk A)
        const float4 v2 = *(const float4*)(p + 512);  // plane d+2 (chunk B)
        const float4 v3 = *(const float4*)(p + 768);  // plane d+3 (chunk B)
        p += 1024;

        // w-pair + d-pair pooling in-register
        const float aA = fmaxf(fmaxf(v0.x, v0.y), fmaxf(v1.x, v1.y)); // wp=2q
        const float bA = fmaxf(fmaxf(v0.z, v0.w), fmaxf(v1.z, v1.w)); // wp=2q+1
        const float aB = fmaxf(fmaxf(v2.x, v2.y), fmaxf(v3.x, v3.y));
        const float bB = fmaxf(fmaxf(v2.z, v2.w), fmaxf(v3.z, v3.w));

        // h-pair pooling with the lane^4 partner
        const float saA = __shfl_xor(aA, 4);
        const float sbA = __shfl_xor(bA, 4);
        const float saB = __shfl_xor(aB, 4);
        const float sbB = __shfl_xor(bB, 4);

        const float p0 = hodd ? fmaxf(aB, saB) : fmaxf(aA, saA);
        const float p1 = hodd ? fmaxf(bB, sbB) : fmaxf(bA, sbA);

        const float4 w0 = *(const float4*)(wp);       // channels for f0
        const float4 w1 = *(const float4*)(wp + 4);   // channels for f0+1
        wp += 512;                                    // +128 features / iter

        acc.x = fmaf(p0, w0.x, fmaf(p1, w1.x, acc.x));
        acc.y = fmaf(p0, w0.y, fmaf(p1, w1.y, acc.y));
        acc.z = fmaf(p0, w0.z, fmaf(p1, w1.z, acc.z));
        acc.w = fmaf(p0, w0.w, fmaf(p1, w1.w, acc.w));
    }

    // in-wave butterfly: all 64 lanes hold disjoint feature partial sums
    #pragma unroll
    for (int off = 32; off; off >>= 1) {
        acc.x += __shfl_xor(acc.x, off);
        acc.y += __shfl_xor(acc.y, off);
        acc.z += __shfl_xor(acc.z, off);
        acc.w += __shfl_xor(acc.w, off);
    }

    if (l == 0) {
        const float4 bi = *(const float4*)bias;
        const float l0 = acc.x + bi.x, l1 = acc.y + bi.y,
                    l2 = acc.z + bi.z, l3 = acc.w + bi.w;
        const float m  = fmaxf(fmaxf(l0, l1), fmaxf(l2, l3));
        const float e0 = expf(l0 - m), e1 = expf(l1 - m),
                    e2 = expf(l2 - m), e3 = expf(l3 - m);
        const float inv = 1.0f / (e0 + e1 + e2 + e3);
        *(float4*)(out + (size_t)b * 4) =
            make_float4(e0 * inv, e1 * inv, e2 * inv, e3 * inv);
    }
}

extern "C" void kernel_launch(void* const* d_in, const int* in_sizes, int n_in,
                              void* d_out, int out_size, void* d_ws, size_t ws_size,
                              hipStream_t stream) {
    const float* x    = (const float*)d_in[0];   // [8192,4,16,16,16]
    const float* W    = (const float*)d_in[1];   // [4,2048]
    const float* bias = (const float*)d_in[2];   // [4]
    float* out = (float*)d_out;                  // [8192,4]
    float* wqt = (float*)d_ws;                   // [2048][4] quantized W^T

    quant_w_kernel<<<8, 256, 0, stream>>>(W, wqt);
    fused_pool_linear_softmax<<<2048, 256, 0, stream>>>(x, wqt, bias, out);
}